// Round 2
// baseline (2436.055 us; speedup 1.0000x reference)
//
#include <hip/hip_runtime.h>
#include <hip/hip_bf16.h>
#include <cstdint>

// Swin block. External I/O: float32. Internal GEMM compute: bf16 MFMA, f32 accum.
#define N_TOK 100352   // 32 * 56 * 56

typedef __attribute__((ext_vector_type(8))) short bf16x8;
typedef __attribute__((ext_vector_type(4))) float f32x4;

__device__ __forceinline__ float b2f(unsigned short u) {
    union { float f; uint32_t i; } v; v.i = ((uint32_t)u) << 16; return v.f;
}
__device__ __forceinline__ unsigned short f2b(float f) {
    uint32_t x = __float_as_uint(f);
    return (unsigned short)((x + 0x7fffu + ((x >> 16) & 1u)) >> 16);
}
__device__ __forceinline__ float gelu_exact(float x) {
    return 0.5f * x * (1.0f + erff(x * 0.70710678118654752440f));
}

// ---------------- weight transpose + f32->bf16 cast (tiny) ----------------
__global__ void transpose_w(const float* __restrict__ W,
                            unsigned short* __restrict__ WT, int K, int Nc) {
    int idx = blockIdx.x * 256 + threadIdx.x;
    if (idx < K * Nc) {
        int k = idx / Nc, n = idx - k * Nc;
        WT[(size_t)n * K + k] = f2b(W[idx]);
    }
}

// ---------------- LayerNorm (optionally fused roll+window-partition) -------
// One wave per output token; lane handles 6 channels (384 = 64*6).
// f32 in, bf16 out (GEMM input).
template<bool PART>
__global__ __launch_bounds__(256) void ln_kernel(const float* __restrict__ xin,
        const float* __restrict__ gamma, const float* __restrict__ beta,
        unsigned short* __restrict__ out)
{
    int t = blockIdx.x * 4 + (threadIdx.x >> 6);
    int lane = threadIdx.x & 63;
    size_t src;
    if (PART) {
        // out token t = bw*49+lw ; source = x[b, (r+3)%56, (c+3)%56]
        int bw = t / 49, lw = t - bw * 49;
        int b = bw >> 6, w = bw & 63;
        int r  = (w >> 3) * 7 + lw / 7;
        int cc = (w & 7) * 7 + lw % 7;
        int sr = (r + 3) % 56, sc = (cc + 3) % 56;
        src = ((size_t)b * 3136 + sr * 56 + sc) * 384;
    } else {
        src = (size_t)t * 384;
    }
    float v[6]; float s = 0.f, ss = 0.f;
    #pragma unroll
    for (int i = 0; i < 6; i++) { v[i] = xin[src + lane + 64 * i]; s += v[i]; ss += v[i] * v[i]; }
    #pragma unroll
    for (int o = 32; o >= 1; o >>= 1) { s += __shfl_xor(s, o, 64); ss += __shfl_xor(ss, o, 64); }
    float mean = s * (1.f / 384.f);
    float var = ss * (1.f / 384.f) - mean * mean;
    var = var < 0.f ? 0.f : var;
    float rstd = rsqrtf(var + 1e-3f);   // keras LN eps
    size_t dst = (size_t)t * 384;
    #pragma unroll
    for (int i = 0; i < 6; i++) {
        int c = lane + 64 * i;
        out[dst + c] = f2b((v[i] - mean) * rstd * gamma[c] + beta[c]);
    }
}

// ---------------- bf16 MFMA GEMM: C = f(A[M,K] @ B[K,Nc] + bias) ----------
// B supplied pre-transposed (BT[Nc][K]). 64x64 block tile, 4 waves of 32x32.
// NOTE: res/C deliberately NOT __restrict__ — fc2 aliases them (same buffer).
template<bool GELU, bool TRANS, bool RES, bool OUTF32>
__global__ __launch_bounds__(256) void gemm_kernel(const unsigned short* __restrict__ A,
        const unsigned short* __restrict__ BT, const float* __restrict__ bias,
        const float* res, void* Cv,
        int M, int K, int Nc)
{
    __shared__ unsigned short As[64 * 40];   // +8 pad: b128 frag reads <=2-way conflicts
    __shared__ unsigned short Bs[64 * 40];
    const int m0 = blockIdx.x * 64, n0 = blockIdx.y * 64;
    const int t = threadIdx.x;
    const int lrow = t >> 2, kg = (t & 3) * 8;
    const int lane = t & 63, w = t >> 6;
    const int wm = (w >> 1) * 32, wn = (w & 1) * 32;
    const int q = lane >> 4, lr = lane & 15;
    f32x4 acc[2][2] = {};
    const unsigned short* Aptr = A + (size_t)(m0 + lrow) * K + kg;
    const unsigned short* Bptr = BT + (size_t)(n0 + lrow) * K + kg;
    for (int k0 = 0; k0 < K; k0 += 32) {
        uint4 av = *(const uint4*)(Aptr + k0);
        uint4 bv = *(const uint4*)(Bptr + k0);
        *(uint4*)(As + lrow * 40 + kg) = av;
        *(uint4*)(Bs + lrow * 40 + kg) = bv;
        __syncthreads();
        bf16x8 a0 = *(const bf16x8*)(As + (wm + lr) * 40 + q * 8);
        bf16x8 a1 = *(const bf16x8*)(As + (wm + 16 + lr) * 40 + q * 8);
        bf16x8 b0 = *(const bf16x8*)(Bs + (wn + lr) * 40 + q * 8);
        bf16x8 b1 = *(const bf16x8*)(Bs + (wn + 16 + lr) * 40 + q * 8);
        acc[0][0] = __builtin_amdgcn_mfma_f32_16x16x32_bf16(a0, b0, acc[0][0], 0, 0, 0);
        acc[0][1] = __builtin_amdgcn_mfma_f32_16x16x32_bf16(a0, b1, acc[0][1], 0, 0, 0);
        acc[1][0] = __builtin_amdgcn_mfma_f32_16x16x32_bf16(a1, b0, acc[1][0], 0, 0, 0);
        acc[1][1] = __builtin_amdgcn_mfma_f32_16x16x32_bf16(a1, b1, acc[1][1], 0, 0, 0);
        __syncthreads();
    }
    #pragma unroll
    for (int mi = 0; mi < 2; mi++)
    #pragma unroll
    for (int ni = 0; ni < 2; ni++)
    #pragma unroll
    for (int r = 0; r < 4; r++) {
        int grow = m0 + wm + mi * 16 + q * 4 + r;          // C/D: row=(lane>>4)*4+reg
        int gcol = n0 + wn + ni * 16 + lr;                 //      col=lane&15
        float v2 = acc[mi][ni][r] + bias[gcol];
        if (GELU) v2 = gelu_exact(v2);
        if (RES) v2 += res[(size_t)grow * Nc + gcol];      // same addr as store below (same thread)
        if (OUTF32) {
            ((float*)Cv)[(size_t)grow * Nc + gcol] = v2;
        } else if (TRANS) {
            ((unsigned short*)Cv)[(size_t)gcol * M + grow] = f2b(v2);  // channel-major qkvT
        } else {
            ((unsigned short*)Cv)[(size_t)grow * Nc + gcol] = f2b(v2);
        }
    }
}

// ---------------- attention over scrambled tiles ---------------------------
// Region mask replicating create_mask: rows/cols 10..52 never written -> 0.
__device__ __forceinline__ int band7(int tt) { return tt < 7 ? 0 : (tt < 10 ? 1 : (tt < 53 ? -1 : 2)); }
__device__ __forceinline__ int region_id(int w, int l) {
    int r = (w >> 3) * 7 + l / 7;
    int c = (w & 7) * 7 + l % 7;
    int br = band7(r), bc = band7(c);
    return (br < 0 || bc < 0) ? 0 : 3 * br + bc;
}

__global__ __launch_bounds__(256) void attn_kernel(const unsigned short* __restrict__ qkvT,
        const float* __restrict__ btab, unsigned short* __restrict__ O)
{
    __shared__ float Qs[1568], Ks[1568], Vs[1568];
    __shared__ float S[49 * 50];
    int g = blockIdx.x;                 // g = b2*12 + h, 24576 total
    int b2 = g / 12, h = g - b2 * 12;
    int ch = g >> 6, j = g & 63;        // channel-major scramble: 1568-elem chunk
    int t = threadIdx.x;
    size_t base = (size_t)ch * N_TOK + (size_t)j * 1568;
    for (int i = t; i < 1568; i += 256) {
        Qs[i] = b2f(qkvT[base + i]);
        Ks[i] = b2f(qkvT[base + (size_t)384 * N_TOK + i]);
        Vs[i] = b2f(qkvT[base + (size_t)768 * N_TOK + i]);
    }
    __syncthreads();
    int wmask = b2 & 63;
    for (int idx = t; idx < 2401; idx += 256) {
        int l = idx / 49, m = idx - l * 49;
        float acc = 0.f;
        #pragma unroll
        for (int d = 0; d < 32; d++) acc += Qs[l * 32 + d] * Ks[m * 32 + d];
        int rel = 13 * ((m % 7 - l % 7 + 6) + (m / 7 - l / 7 + 6));
        acc += btab[rel * 12 + h];
        if (region_id(wmask, l) != region_id(wmask, m)) acc -= 100.f;
        S[l * 50 + m] = acc;
    }
    __syncthreads();
    if (t < 49) {
        float mx = -1e30f;
        for (int m = 0; m < 49; m++) mx = fmaxf(mx, S[t * 50 + m]);
        float sum = 0.f;
        for (int m = 0; m < 49; m++) { float e = __expf(S[t * 50 + m] - mx); S[t * 50 + m] = e; sum += e; }
        float inv = 1.f / sum;
        for (int m = 0; m < 49; m++) S[t * 50 + m] *= inv;
    }
    __syncthreads();
    for (int idx = t; idx < 1568; idx += 256) {
        int l = idx >> 5, d = idx & 31;
        float acc = 0.f;
        for (int m = 0; m < 49; m++) acc += S[l * 50 + m] * Vs[m * 32 + d];
        O[((size_t)b2 * 49 + l) * 384 + h * 32 + d] = f2b(acc);  // transpose(0,2,1,3)
    }
}

// ---------------- window reverse + roll(+3,+3) + residual (f32 out) --------
__global__ __launch_bounds__(384) void scatter_res(const float* __restrict__ x,
        const unsigned short* __restrict__ O2, float* __restrict__ X1)
{
    int bi = blockIdx.x;                      // (b, rr, cc) output token
    int b = bi / 3136, tt = bi - b * 3136;
    int rr = tt / 56, cc = tt - rr * 56;
    int r2 = (rr + 53) % 56, c2 = (cc + 53) % 56;   // un-roll by +3
    int row = (b * 64 + (r2 / 7) * 8 + (c2 / 7)) * 49 + (r2 % 7) * 7 + (c2 % 7);
    int c = threadIdx.x;
    size_t o = (size_t)bi * 384 + c;
    X1[o] = x[o] + b2f(O2[(size_t)row * 384 + c]);
}

extern "C" void kernel_launch(void* const* d_in, const int* in_sizes, int n_in,
                              void* d_out, int out_size, void* d_ws, size_t ws_size,
                              hipStream_t stream)
{
    (void)in_sizes; (void)n_in; (void)out_size; (void)ws_size;
    const float* x      = (const float*)d_in[0];
    const float* gamma  = (const float*)d_in[1];
    const float* beta   = (const float*)d_in[2];
    const float* w_qkv  = (const float*)d_in[3];
    const float* b_qkv  = (const float*)d_in[4];
    const float* btab   = (const float*)d_in[5];
    const float* w_att  = (const float*)d_in[6];
    const float* b_att  = (const float*)d_in[7];
    const float* w_fc1  = (const float*)d_in[8];
    const float* b_fc1  = (const float*)d_in[9];
    const float* w_fc2  = (const float*)d_in[10];
    const float* b_fc2  = (const float*)d_in[11];
    float* out = (float*)d_out;

    // ws layout (bytes): bufA 77.1MB | bufQ 308.3MB (qkvT 231MB + attnO 77MB tail,
    // then fc1out full) | weights 3.5MB  => ~389MB total.
    // x1 residual (f32, 154MB) lives in d_out itself.
    char* ws = (char*)d_ws;
    const size_t SA = (size_t)N_TOK * 384 * 2;
    const size_t SQ = (size_t)N_TOK * 1536 * 2;
    unsigned short* bufA = (unsigned short*)(ws);            // h_win -> O2 -> h2
    unsigned short* bufQ = (unsigned short*)(ws + SA);       // qkvT -> fc1out
    unsigned short* bufO = bufQ + (size_t)1152 * N_TOK;      // attn out, in qkvT's dead tail
    unsigned short* wqkvT = (unsigned short*)(ws + SA + SQ);
    unsigned short* wattT = wqkvT + 384 * 1152;
    unsigned short* wfc1T = wattT + 384 * 384;
    unsigned short* wfc2T = wfc1T + 384 * 1536;
    float* bufX = out;                                       // x after attn residual

    transpose_w<<<(384 * 1152 + 255) / 256, 256, 0, stream>>>(w_qkv, wqkvT, 384, 1152);
    transpose_w<<<(384 * 384 + 255) / 256, 256, 0, stream>>>(w_att, wattT, 384, 384);
    transpose_w<<<(384 * 1536 + 255) / 256, 256, 0, stream>>>(w_fc1, wfc1T, 384, 1536);
    transpose_w<<<(1536 * 384 + 255) / 256, 256, 0, stream>>>(w_fc2, wfc2T, 1536, 384);

    // 1. LN + roll(-3,-3) + window partition (f32 -> bf16)
    ln_kernel<true><<<N_TOK / 4, 256, 0, stream>>>(x, gamma, beta, bufA);
    // 2. qkv = gelu(h @ w_qkv + b), stored channel-major [1152][N_TOK]
    gemm_kernel<true, true, false, false><<<dim3(N_TOK / 64, 1152 / 64), 256, 0, stream>>>(
        bufA, wqkvT, b_qkv, nullptr, bufQ, N_TOK, 384, 1152);
    // 3. scrambled-window attention
    attn_kernel<<<24576, 256, 0, stream>>>(bufQ, btab, bufO);
    // 4. out = gelu(O @ w_att + b_att)
    gemm_kernel<true, false, false, false><<<dim3(N_TOK / 64, 384 / 64), 256, 0, stream>>>(
        bufO, wattT, b_att, nullptr, bufA, N_TOK, 384, 384);
    // 5. window reverse + roll(+3,+3) + residual -> x1 (f32, in d_out)
    scatter_res<<<N_TOK, 384, 0, stream>>>(x, bufA, bufX);
    // 6. LN for MLP (f32 -> bf16)
    ln_kernel<false><<<N_TOK / 4, 256, 0, stream>>>(bufX, gamma, beta, bufA);
    // 7. fc1 + gelu
    gemm_kernel<true, false, false, false><<<dim3(N_TOK / 64, 1536 / 64), 256, 0, stream>>>(
        bufA, wfc1T, b_fc1, nullptr, bufQ, N_TOK, 384, 1536);
    // 8. fc2 + residual -> out (f32; res aliases C element-wise, same thread)
    gemm_kernel<false, false, true, true><<<dim3(N_TOK / 64, 384 / 64), 256, 0, stream>>>(
        bufQ, wfc2T, b_fc2, bufX, out, N_TOK, 1536, 384);
}

// Round 3
// 1477.462 us; speedup vs baseline: 1.6488x; 1.6488x over previous
//
#include <hip/hip_runtime.h>
#include <hip/hip_bf16.h>
#include <cstdint>

// Swin block. External I/O: float32. Internal GEMM compute: bf16 MFMA, f32 accum.
#define N_TOK 100352   // 32 * 56 * 56

typedef unsigned short u16;
typedef __attribute__((ext_vector_type(8))) short bf16x8;
typedef __attribute__((ext_vector_type(4))) float f32x4;

__device__ __forceinline__ float b2f(u16 u) {
    union { float f; uint32_t i; } v; v.i = ((uint32_t)u) << 16; return v.f;
}
__device__ __forceinline__ u16 f2b(float f) {
    uint32_t x = __float_as_uint(f);
    return (u16)((x + 0x7fffu + ((x >> 16) & 1u)) >> 16);
}
__device__ __forceinline__ float gelu_exact(float x) {
    return 0.5f * x * (1.0f + erff(x * 0.70710678118654752440f));
}

// async global->LDS, 16B per lane; lds dest = wave-uniform base + lane*16
__device__ __forceinline__ void gload16(const void* g, void* l) {
    __builtin_amdgcn_global_load_lds(
        (const __attribute__((address_space(1))) unsigned int*)(uintptr_t)g,
        (__attribute__((address_space(3))) unsigned int*)(unsigned int)(uintptr_t)l,
        16, 0, 0);
}

// ---------------- weight transpose + f32->bf16 cast (tiny) ----------------
__global__ void transpose_w(const float* __restrict__ W,
                            u16* __restrict__ WT, int K, int Nc) {
    int idx = blockIdx.x * 256 + threadIdx.x;
    if (idx < K * Nc) {
        int k = idx / Nc, n = idx - k * Nc;
        WT[(size_t)n * K + k] = f2b(W[idx]);
    }
}

// ---------------- LayerNorm fused with roll(-3,-3) + window partition ------
template<bool PART>
__global__ __launch_bounds__(256) void ln_kernel(const float* __restrict__ xin,
        const float* __restrict__ gamma, const float* __restrict__ beta,
        u16* __restrict__ out)
{
    int t = blockIdx.x * 4 + (threadIdx.x >> 6);
    int lane = threadIdx.x & 63;
    size_t src;
    if (PART) {
        int bw = t / 49, lw = t - bw * 49;
        int b = bw >> 6, w = bw & 63;
        int r  = (w >> 3) * 7 + lw / 7;
        int cc = (w & 7) * 7 + lw % 7;
        int sr = (r + 3) % 56, sc = (cc + 3) % 56;
        src = ((size_t)b * 3136 + sr * 56 + sc) * 384;
    } else {
        src = (size_t)t * 384;
    }
    float v[6]; float s = 0.f, ss = 0.f;
    #pragma unroll
    for (int i = 0; i < 6; i++) { v[i] = xin[src + lane + 64 * i]; s += v[i]; ss += v[i] * v[i]; }
    #pragma unroll
    for (int o = 32; o >= 1; o >>= 1) { s += __shfl_xor(s, o, 64); ss += __shfl_xor(ss, o, 64); }
    float mean = s * (1.f / 384.f);
    float var = ss * (1.f / 384.f) - mean * mean;
    var = var < 0.f ? 0.f : var;
    float rstd = rsqrtf(var + 1e-3f);
    size_t dst = (size_t)t * 384;
    #pragma unroll
    for (int i = 0; i < 6; i++) {
        int c = lane + 64 * i;
        out[dst + c] = f2b((v[i] - mean) * rstd * gamma[c] + beta[c]);
    }
}

// ---------------- bf16 MFMA GEMM, m97 structure ----------------------------
// C[M,Nc] = f(A[M,K] @ BT[Nc,K]^T + bias). 128x128 tile, 4 waves x (4x4 MFMA).
// global_load_lds staging (no LDS padding - dest is lane-contiguous).
// TRANS: channel-major store C[col][row] via LDS restage (coalesced uint4).
template<bool GELU, bool TRANS, bool RES, bool OUTF32>
__global__ __launch_bounds__(256) void gemm128(const u16* __restrict__ A,
        const u16* __restrict__ BT, const float* __restrict__ bias,
        const float* res, void* Cv, int M, int K, int Nc)
{
    __shared__ u16 As[4352];   // main loop: [128][32]; TRANS epilogue: [32][136]
    __shared__ u16 Bs[4352];
    const int n0 = blockIdx.x * 128, m0 = blockIdx.y * 128;   // x-fast => A-tile L2 reuse
    const int t = threadIdx.x, w = t >> 6, lane = t & 63;
    const int lr = lane & 15, q = lane >> 4;
    const int wm = (w >> 1) * 64, wn = (w & 1) * 64;
    const int srow = w * 32 + (lane >> 2);     // staging row for this lane
    const int scol = (lane & 3) * 8;           // staging k-offset (elements)
    const u16* ga = A + (size_t)(m0 + srow) * K + scol;
    const u16* gb = BT + (size_t)(n0 + srow) * K + scol;
    u16* la = As + w * 32 * 32;
    u16* lb = Bs + w * 32 * 32;
    f32x4 acc[4][4] = {};
    for (int k0 = 0; k0 < K; k0 += 32) {
        gload16(ga + k0, la);
        gload16(ga + k0 + (size_t)16 * K, la + 16 * 32);
        gload16(gb + k0, lb);
        gload16(gb + k0 + (size_t)16 * K, lb + 16 * 32);
        __syncthreads();
        bf16x8 af[4], bf[4];
        #pragma unroll
        for (int i = 0; i < 4; i++) {
            af[i] = *(const bf16x8*)(As + (wm + i * 16 + lr) * 32 + q * 8);
            bf[i] = *(const bf16x8*)(Bs + (wn + i * 16 + lr) * 32 + q * 8);
        }
        #pragma unroll
        for (int mi = 0; mi < 4; mi++)
        #pragma unroll
        for (int ni = 0; ni < 4; ni++)
            acc[mi][ni] = __builtin_amdgcn_mfma_f32_16x16x32_bf16(af[mi], bf[ni], acc[mi][ni], 0, 0, 0);
        __syncthreads();
    }
    if (!TRANS) {
        #pragma unroll
        for (int mi = 0; mi < 4; mi++)
        #pragma unroll
        for (int ni = 0; ni < 4; ni++)
        #pragma unroll
        for (int r = 0; r < 4; r++) {
            int grow = m0 + wm + mi * 16 + q * 4 + r;   // C/D: row=(lane>>4)*4+reg
            int gcol = n0 + wn + ni * 16 + lr;          //      col=lane&15
            float v = acc[mi][ni][r] + bias[gcol];
            if (GELU) v = gelu_exact(v);
            if (RES) v += res[(size_t)grow * Nc + gcol];
            if (OUTF32) ((float*)Cv)[(size_t)grow * Nc + gcol] = v;
            else        ((u16*)Cv)[(size_t)grow * Nc + gcol] = f2b(v);
        }
    } else {
        // restage through LDS: [32 cols][136 rows-padded], then coalesced col stores
        u16* cb = (w & 1) ? Bs : As;
        #pragma unroll
        for (int p = 0; p < 2; p++) {
            __syncthreads();
            #pragma unroll
            for (int nn = 0; nn < 2; nn++) {
                int ni = p * 2 + nn;
                #pragma unroll
                for (int mi = 0; mi < 4; mi++)
                #pragma unroll
                for (int r = 0; r < 4; r++) {
                    float v = acc[mi][ni][r] + bias[n0 + wn + ni * 16 + lr];
                    if (GELU) v = gelu_exact(v);
                    cb[(nn * 16 + lr) * 136 + wm + mi * 16 + q * 4 + r] = f2b(v);
                }
            }
            __syncthreads();
            int buf = t >> 7, c = (t >> 2) & 31, rs = (t & 3) * 32;
            const u16* sb = buf ? Bs : As;
            u16* dst = (u16*)Cv + (size_t)(n0 + buf * 64 + p * 32 + c) * M + m0 + rs;
            #pragma unroll
            for (int i = 0; i < 4; i++)
                *(uint4*)(dst + i * 8) = *(const uint4*)(sb + c * 136 + rs + i * 8);
        }
    }
}

// ---------------- MFMA attention over scrambled tiles ----------------------
__device__ __forceinline__ int band7(int tt) { return tt < 7 ? 0 : (tt < 10 ? 1 : (tt < 53 ? -1 : 2)); }
__device__ __forceinline__ int region_id(int w, int l) {
    int r = (w >> 3) * 7 + l / 7;
    int c = (w & 7) * 7 + l % 7;
    int br = band7(r), bc = band7(c);
    return (br < 0 || bc < 0) ? 0 : 3 * br + bc;
}

__global__ __launch_bounds__(256) void attn_mfma(const u16* __restrict__ qkvT,
        const float* __restrict__ btab, u16* __restrict__ O)
{
    __shared__ u16 Qs[64 * 40];    // [l][d], stride 40 (b128-friendly, as gemm)
    __shared__ u16 Ks[64 * 40];    // [m][d]
    __shared__ u16 Vt[32 * 72];    // [d][m] (transposed; cols m>=49 zeroed)
    __shared__ u16 Ps[64 * 72];    // [l][m] softmax probs, bf16
    __shared__ float bias_l[313];
    int g = blockIdx.x;                 // g = b2*12 + h
    int b2 = g / 12, h = g - b2 * 12;
    int ch = g >> 6, j = g & 63;        // channel-major scramble: 1568-elem chunk
    int t = threadIdx.x;
    size_t base = (size_t)ch * N_TOK + (size_t)j * 1568;
    const u16* qg = qkvT + base;
    const u16* kg = qkvT + base + (size_t)384 * N_TOK;
    const u16* vg = qkvT + base + (size_t)768 * N_TOK;
    for (int i = t; i < 32 * 72 / 2; i += 256) ((unsigned int*)Vt)[i] = 0;
    for (int i = t; i < 313; i += 256) bias_l[i] = btab[i * 12 + h];
    __syncthreads();
    for (int ii = t; ii < 784; ii += 256) {
        int i = ii * 2;
        int l = i >> 5, d = i & 31;
        *(unsigned int*)&Qs[l * 40 + d] = *(const unsigned int*)&qg[i];
        *(unsigned int*)&Ks[l * 40 + d] = *(const unsigned int*)&kg[i];
        unsigned int vv = *(const unsigned int*)&vg[i];
        Vt[d * 72 + l] = (u16)(vv & 0xffffu);
        Vt[(d + 1) * 72 + l] = (u16)(vv >> 16);
    }
    __syncthreads();
    int w = t >> 6, lane = t & 63, lr = lane & 15, q = lane >> 4;
    // ---- QK^T: wave w computes S rows w*16..w*16+15, all 64 cols ----
    f32x4 S[4] = {};
    {
        bf16x8 a = *(const bf16x8*)(Qs + (w * 16 + lr) * 40 + q * 8);
        #pragma unroll
        for (int ni = 0; ni < 4; ni++) {
            bf16x8 b = *(const bf16x8*)(Ks + (ni * 16 + lr) * 40 + q * 8);
            S[ni] = __builtin_amdgcn_mfma_f32_16x16x32_bf16(a, b, S[ni], 0, 0, 0);
        }
    }
    // ---- bias + mask (rows/cols >=49 forced to -1e30) ----
    int wmask = b2 & 63;
    int lrow[4], l7[4], ld7[4], lreg[4];
    #pragma unroll
    for (int r = 0; r < 4; r++) {
        lrow[r] = w * 16 + q * 4 + r;
        int l = lrow[r] < 49 ? lrow[r] : 0;
        l7[r] = l % 7; ld7[r] = l / 7; lreg[r] = region_id(wmask, l);
    }
    #pragma unroll
    for (int ni = 0; ni < 4; ni++) {
        int m = ni * 16 + lr;
        bool mv = m < 49;
        int mm = mv ? m : 0;
        int m7 = mm % 7, md7 = mm / 7, mreg = region_id(wmask, mm);
        #pragma unroll
        for (int r = 0; r < 4; r++) {
            float val;
            if (mv && lrow[r] < 49) {
                int rel = 13 * ((m7 - l7[r] + 6) + (md7 - ld7[r] + 6));
                val = S[ni][r] + bias_l[rel];
                if (mreg != lreg[r]) val -= 100.f;
            } else {
                val = -1e30f;
            }
            S[ni][r] = val;
        }
    }
    // ---- softmax fully in registers (row spans 16 lanes of this quad) ----
    float inv[4];
    #pragma unroll
    for (int r = 0; r < 4; r++) {
        float m_ = fmaxf(fmaxf(S[0][r], S[1][r]), fmaxf(S[2][r], S[3][r]));
        m_ = fmaxf(m_, __shfl_xor(m_, 1, 64));
        m_ = fmaxf(m_, __shfl_xor(m_, 2, 64));
        m_ = fmaxf(m_, __shfl_xor(m_, 4, 64));
        m_ = fmaxf(m_, __shfl_xor(m_, 8, 64));
        #pragma unroll
        for (int ni = 0; ni < 4; ni++) S[ni][r] = __expf(S[ni][r] - m_);
        float s_ = S[0][r] + S[1][r] + S[2][r] + S[3][r];
        s_ += __shfl_xor(s_, 1, 64);
        s_ += __shfl_xor(s_, 2, 64);
        s_ += __shfl_xor(s_, 4, 64);
        s_ += __shfl_xor(s_, 8, 64);
        inv[r] = 1.f / s_;
    }
    #pragma unroll
    for (int ni = 0; ni < 4; ni++)
    #pragma unroll
    for (int r = 0; r < 4; r++)
        Ps[(w * 16 + q * 4 + r) * 72 + ni * 16 + lr] = f2b(S[ni][r] * inv[r]);
    __syncthreads();
    // ---- PV: O rows w*16..+15, 32 cols, K=64 ----
    f32x4 Oa[2] = {};
    #pragma unroll
    for (int kc = 0; kc < 2; kc++) {
        bf16x8 a = *(const bf16x8*)(Ps + (w * 16 + lr) * 72 + kc * 32 + q * 8);
        #pragma unroll
        for (int n2 = 0; n2 < 2; n2++) {
            bf16x8 b = *(const bf16x8*)(Vt + (n2 * 16 + lr) * 72 + kc * 32 + q * 8);
            Oa[n2] = __builtin_amdgcn_mfma_f32_16x16x32_bf16(a, b, Oa[n2], 0, 0, 0);
        }
    }
    size_t ob = (size_t)b2 * 49 * 384 + (size_t)h * 32;
    #pragma unroll
    for (int n2 = 0; n2 < 2; n2++)
    #pragma unroll
    for (int r = 0; r < 4; r++) {
        int l = w * 16 + q * 4 + r;
        if (l < 49) O[ob + (size_t)l * 384 + n2 * 16 + lr] = f2b(Oa[n2][r]);
    }
}

// ------- window reverse + roll(+3,+3) + residual + LN (fused) --------------
__global__ __launch_bounds__(384) void scatter_ln(const float* __restrict__ x,
        const u16* __restrict__ O2, const float* __restrict__ gamma,
        const float* __restrict__ beta, float* __restrict__ X1, u16* __restrict__ H2)
{
    int bi = blockIdx.x;
    int b = bi / 3136, tt = bi - b * 3136;
    int rr = tt / 56, cc = tt - rr * 56;
    int r2 = (rr + 53) % 56, c2 = (cc + 53) % 56;
    int row = (b * 64 + (r2 / 7) * 8 + (c2 / 7)) * 49 + (r2 % 7) * 7 + (c2 % 7);
    int c = threadIdx.x;
    size_t o = (size_t)bi * 384 + c;
    float v = x[o] + b2f(O2[(size_t)row * 384 + c]);
    X1[o] = v;
    __shared__ float red[12];
    float s = v, ss = v * v;
    #pragma unroll
    for (int off = 32; off >= 1; off >>= 1) { s += __shfl_xor(s, off, 64); ss += __shfl_xor(ss, off, 64); }
    int wid = c >> 6;
    if ((c & 63) == 0) { red[wid] = s; red[6 + wid] = ss; }
    __syncthreads();
    s = red[0] + red[1] + red[2] + red[3] + red[4] + red[5];
    ss = red[6] + red[7] + red[8] + red[9] + red[10] + red[11];
    float mean = s * (1.f / 384.f);
    float var = ss * (1.f / 384.f) - mean * mean;
    var = var < 0.f ? 0.f : var;
    float rstd = rsqrtf(var + 1e-3f);
    H2[o] = f2b((v - mean) * rstd * gamma[c] + beta[c]);
}

extern "C" void kernel_launch(void* const* d_in, const int* in_sizes, int n_in,
                              void* d_out, int out_size, void* d_ws, size_t ws_size,
                              hipStream_t stream)
{
    (void)in_sizes; (void)n_in; (void)out_size; (void)ws_size;
    const float* x      = (const float*)d_in[0];
    const float* gamma  = (const float*)d_in[1];
    const float* beta   = (const float*)d_in[2];
    const float* w_qkv  = (const float*)d_in[3];
    const float* b_qkv  = (const float*)d_in[4];
    const float* btab   = (const float*)d_in[5];
    const float* w_att  = (const float*)d_in[6];
    const float* b_att  = (const float*)d_in[7];
    const float* w_fc1  = (const float*)d_in[8];
    const float* b_fc1  = (const float*)d_in[9];
    const float* w_fc2  = (const float*)d_in[10];
    const float* b_fc2  = (const float*)d_in[11];
    float* out = (float*)d_out;

    // ws: bufA 77MB | bufQ 308MB | weights 3.5MB = 389MB (same as round 2).
    // Buffer lifetimes: bufA = h_win -> attnO -> H2 ; bufQ = qkvT -> O2 -> fc1out.
    // X1 (f32 residual) lives in d_out.
    char* ws = (char*)d_ws;
    const size_t SA = (size_t)N_TOK * 384 * 2;
    const size_t SQ = (size_t)N_TOK * 1536 * 2;
    u16* bufA = (u16*)(ws);
    u16* bufQ = (u16*)(ws + SA);
    u16* wqkvT = (u16*)(ws + SA + SQ);
    u16* wattT = wqkvT + 384 * 1152;
    u16* wfc1T = wattT + 384 * 384;
    u16* wfc2T = wfc1T + 384 * 1536;
    float* bufX = out;

    transpose_w<<<(384 * 1152 + 255) / 256, 256, 0, stream>>>(w_qkv, wqkvT, 384, 1152);
    transpose_w<<<(384 * 384 + 255) / 256, 256, 0, stream>>>(w_att, wattT, 384, 384);
    transpose_w<<<(384 * 1536 + 255) / 256, 256, 0, stream>>>(w_fc1, wfc1T, 384, 1536);
    transpose_w<<<(1536 * 384 + 255) / 256, 256, 0, stream>>>(w_fc2, wfc2T, 1536, 384);

    // 1. LN + roll(-3,-3) + window partition  (x -> bufA, bf16)
    ln_kernel<true><<<N_TOK / 4, 256, 0, stream>>>(x, gamma, beta, bufA);
    // 2. qkvT = gelu(h @ w_qkv + b) stored channel-major [1152][N_TOK] (-> bufQ)
    gemm128<true, true, false, false><<<dim3(1152 / 128, N_TOK / 128), 256, 0, stream>>>(
        bufA, wqkvT, b_qkv, nullptr, bufQ, N_TOK, 384, 1152);
    // 3. attention (qkvT -> bufA)
    attn_mfma<<<24576, 256, 0, stream>>>(bufQ, btab, bufA);
    // 4. O2 = gelu(attnO @ w_att + b_att)  (bufA -> bufQ[0:77MB), qkvT dead)
    gemm128<true, false, false, false><<<dim3(384 / 128, N_TOK / 128), 256, 0, stream>>>(
        bufA, wattT, b_att, nullptr, bufQ, N_TOK, 384, 384);
    // 5. window reverse + roll + residual + LN2  (-> X1 in d_out, H2 in bufA)
    scatter_ln<<<N_TOK, 384, 0, stream>>>(x, bufQ, gamma, beta, bufX, bufA);
    // 6. fc1 + gelu  (bufA -> bufQ full, O2 dead)
    gemm128<true, false, false, false><<<dim3(1536 / 128, N_TOK / 128), 256, 0, stream>>>(
        bufA, wfc1T, b_fc1, nullptr, bufQ, N_TOK, 384, 1536);
    // 7. fc2 + residual -> out (f32; res aliases C element-wise, same thread)
    gemm128<false, false, true, true><<<dim3(384 / 128, N_TOK / 128), 256, 0, stream>>>(
        bufQ, wfc2T, b_fc2, bufX, out, N_TOK, 1536, 384);
}